// Round 9
// baseline (1738.154 us; speedup 1.0000x reference)
//
#include <hip/hip_runtime.h>
#include <hip/hip_bf16.h>
#include <math.h>

typedef __hip_bfloat16 bf16;
typedef __bf16 bf16x8 __attribute__((ext_vector_type(8)));
typedef float f32x4 __attribute__((ext_vector_type(4)));

__device__ __forceinline__ float b2f(bf16 v){ return __bfloat162float(v); }
__device__ __forceinline__ bf16  f2b(float v){ return __float2bfloat16(v); }

// tanh-form gelu (~6 VALU ops); max |diff vs erf-gelu| ~1e-3
__device__ __forceinline__ float gelu_f(float v){
    float y = v * (1.f + 0.044715f * v * v);
    return v / (1.f + __expf(-1.5957691216057308f * y));
}

// async global->LDS, 16B per lane; LDS dest = wave-uniform base + lane*16
__device__ __forceinline__ void gl_lds16(const bf16* g, bf16* l) {
    __builtin_amdgcn_global_load_lds((const __attribute__((address_space(1))) unsigned int*)g,
                                     (__attribute__((address_space(3))) unsigned int*)l, 16, 0, 0);
}

__device__ __forceinline__ uint2 pack4bf(const float* v){
    union { unsigned short e[4]; uint2 u; } pk;
    #pragma unroll
    for (int r = 0; r < 4; r++) pk.e[r] = __builtin_bit_cast(unsigned short, f2b(v[r]));
    return pk.u;
}

// raw barrier without the compiler's vmcnt(0) drain; sched fences pin phase structure
__device__ __forceinline__ void phase_bar() {
    __builtin_amdgcn_sched_barrier(0);
    __builtin_amdgcn_s_barrier();
    __builtin_amdgcn_sched_barrier(0);
}

// L2-supertile block mapping (BM=256 kernels): each XCD owns 4 fixed mt-panels,
// sweeps nt in chunks of ntc. slot order within XCD: chunk-major, then mt, then nt.
__device__ __forceinline__ void supertile_map(int bid, int ntc, int& mt, int& nt) {
    const int slot = bid >> 3, xcd = bid & 7;
    const int g = 4 * ntc;
    const int chunk = slot / g;
    const int r = slot - chunk * g;
    const int ml = r / ntc;
    mt = xcd * 4 + ml;
    nt = chunk * ntc + (r - ml * ntc);
}

// BM=128 variant: each XCD owns 8 fixed mt-panels (64 total), nt chunks of ntc.
__device__ __forceinline__ void supertile_map8(int bid, int ntc, int& mt, int& nt) {
    const int slot = bid >> 3, xcd = bid & 7;
    const int g = 8 * ntc;
    const int chunk = slot / g;
    const int r = slot - chunk * g;
    const int ml = r / ntc;
    mt = xcd * 8 + ml;
    nt = chunk * ntc + (r - ml * ntc);
}

// ---------------- deck means ----------------
__global__ __launch_bounds__(256) void deckmean_k(const int* __restrict__ deck, const int* __restrict__ opp,
                                                  const float* __restrict__ tok, float* __restrict__ deckm)
{
    int b = blockIdx.x, w = blockIdx.y;
    const int* dk = (w ? opp : deck) + b * 8;
    int idx[8];
    #pragma unroll
    for (int j = 0; j < 8; j++) idx[j] = dk[j];
    float* out = deckm + (size_t)(w * 16 + b) * 768;
    for (int d = threadIdx.x; d < 768; d += 256) {
        float s = 0.f;
        #pragma unroll
        for (int j = 0; j < 8; j++) s += tok[(size_t)idx[j] * 768 + d];
        out[d] = s * 0.125f;
    }
}

// ---------------- mask + last_idx ----------------
__global__ __launch_bounds__(512) void mask_k(const int* __restrict__ cards, int* __restrict__ maskb,
                                              int* __restrict__ lastidx)
{
    int b = blockIdx.x, t = threadIdx.x;
    int m = (cards[b * 512 + t] != 0) ? 1 : 0;
    maskb[b * 512 + t] = m;
    __shared__ int red[512];
    red[t] = m; __syncthreads();
    for (int st = 256; st > 0; st >>= 1) { if (t < st) red[t] += red[t + st]; __syncthreads(); }
    if (t == 0) {
        int cnt = red[0];
        if (cnt == 0) { maskb[b * 512] = 1; cnt = 1; }  // all-pad fix
        lastidx[b] = cnt - 1;
    }
}

// ---------------- embedding sum -> fp32 residual stream ----------------
__global__ __launch_bounds__(256) void embed_k(const int* __restrict__ cards, const int* __restrict__ players,
                                               const float* __restrict__ tok, const float* __restrict__ pemb,
                                               const float* __restrict__ pos, const float* __restrict__ deckm,
                                               float* __restrict__ x)
{
    int t = blockIdx.x;
    int b = t >> 9, ti = t & 511;
    int cd = cards[t];
    int p = players[t]; p = p < 0 ? 0 : (p > 1 ? 1 : p);
    const float* tr  = tok  + (size_t)cd * 768;
    const float* pr  = pemb + (size_t)p  * 768;
    const float* po  = pos  + (size_t)ti * 768;
    const float* dm = deckm + (size_t)b * 768;
    const float* om = deckm + (size_t)(16 + b) * 768;
    float* xr = x + (size_t)t * 768;
    for (int d = threadIdx.x; d < 768; d += 256)
        xr[d] = tr[d] + pr[d] + po[d] + dm[d] + om[d];
}

// ---------------- layernorm (vectorized): fp32 in -> bf16 out, 192 thr/row ----------------
__global__ __launch_bounds__(192) void ln_k(const float* __restrict__ x, const float* __restrict__ s,
                                            const float* __restrict__ b, bf16* __restrict__ out)
{
    int row = blockIdx.x, tid = threadIdx.x;
    float4 v = ((const float4*)(x + (size_t)row * 768))[tid];
    float sum = v.x + v.y + v.z + v.w;
    float sq  = v.x * v.x + v.y * v.y + v.z * v.z + v.w * v.w;
    #pragma unroll
    for (int off = 32; off > 0; off >>= 1) {
        sum += __shfl_xor(sum, off, 64);
        sq  += __shfl_xor(sq,  off, 64);
    }
    __shared__ float red[6];
    int wv = tid >> 6;
    if ((tid & 63) == 0) { red[wv] = sum; red[3 + wv] = sq; }
    __syncthreads();
    float S = red[0] + red[1] + red[2];
    float Q = red[3] + red[4] + red[5];
    float mean = S * (1.f / 768.f);
    float var  = Q * (1.f / 768.f) - mean * mean;
    float rstd = rsqrtf(var + 1e-5f);
    float4 sv = ((const float4*)s)[tid];
    float4 bv = ((const float4*)b)[tid];
    float o[4] = { (v.x - mean) * rstd * sv.x + bv.x, (v.y - mean) * rstd * sv.y + bv.y,
                   (v.z - mean) * rstd * sv.z + bv.z, (v.w - mean) * rstd * sv.w + bv.w };
    ((uint2*)(out + (size_t)row * 768))[tid] = pack4bf(o);
}

// ---------------- weight transpose+downcast: 64x64 tiles, in-register 4x4 transpose ----------------
// tiles: qkv 12x36=432, proj 12x12=144, fc1 12x48=576, fc2 48x12=576 -> 1728 blocks
__global__ __launch_bounds__(256) void transpose4_k(const float* __restrict__ qw, const float* __restrict__ pw,
                                                    const float* __restrict__ f1, const float* __restrict__ f2,
                                                    bf16* __restrict__ oq, bf16* __restrict__ op,
                                                    bf16* __restrict__ o1, bf16* __restrict__ o2)
{
    int t = blockIdx.x;
    const float* in; bf16* out; int K, N, nbx;
    if (t < 432)       { in = qw; out = oq; K = 768;  N = 2304; nbx = 36; }
    else if (t < 576)  { in = pw; out = op; K = 768;  N = 768;  t -= 432;  nbx = 12; }
    else if (t < 1152) { in = f1; out = o1; K = 768;  N = 3072; t -= 576;  nbx = 48; }
    else               { in = f2; out = o2; K = 3072; N = 768;  t -= 1152; nbx = 12; }
    int n0 = (t % nbx) * 64, k0 = (t / nbx) * 64;
    int kq = threadIdx.x & 15, nq = threadIdx.x >> 4;
    float4 rr[4];
    #pragma unroll
    for (int r = 0; r < 4; r++)
        rr[r] = *(const float4*)&in[(size_t)(k0 + kq * 4 + r) * N + n0 + nq * 4];
    const float* fp = (const float*)rr;
    #pragma unroll
    for (int c = 0; c < 4; c++) {
        float v[4] = { fp[c], fp[4 + c], fp[8 + c], fp[12 + c] };
        *(uint2*)&out[(size_t)(n0 + nq * 4 + c) * K + k0 + kq * 4] = pack4bf(v);
    }
}

// ---------------- MFMA GEMM 128x128 TLP (qkv, fc1): 2 blocks/CU, named double-buffer, bf16 out ----
// (round-8 kernel, unchanged)
__global__ __launch_bounds__(256, 2) void gemm2b_k(const bf16* __restrict__ A, const bf16* __restrict__ BT,
                                                   const float* __restrict__ bias, bf16* __restrict__ out,
                                                   int N, int K, int act, int ntc)
{
    __shared__ __align__(16) bf16 DA0[128 * 64];
    __shared__ __align__(16) bf16 DA1[128 * 64];
    __shared__ __align__(16) bf16 DB0[128 * 64];
    __shared__ __align__(16) bf16 DB1[128 * 64];

    const int tid  = threadIdx.x;
    const int lane = tid & 63, wid = tid >> 6;        // 4 waves
    const int quad = lane >> 4, l16 = lane & 15;
    const int wr = wid >> 1, wc = wid & 1;
    const int cg0 = quad ^ (l16 & 7);
    const int cg1 = cg0 ^ 4;

    int mt, nt;
    supertile_map8((int)blockIdx.x, ntc, mt, nt);
    const int m0 = mt * 128, n0 = nt * 128;

    const int srow = wid * 8 + (lane >> 3);           // [0,32)
    const int scg  = (lane & 7) ^ (lane >> 3);        // pre-swizzled global col-group
    const bf16* sa[4]; const bf16* sb[4];
    #pragma unroll
    for (int s = 0; s < 4; s++) {
        sa[s] = A  + (size_t)(m0 + s * 32 + srow) * K + scg * 8;
        sb[s] = BT + (size_t)(n0 + s * 32 + srow) * K + scg * 8;
    }

#define D_STG8(NA, NB) { \
    gl_lds16(sa[0], &NA[(0 * 32 + wid * 8) * 64]); gl_lds16(sa[1], &NA[(1 * 32 + wid * 8) * 64]); \
    gl_lds16(sa[2], &NA[(2 * 32 + wid * 8) * 64]); gl_lds16(sa[3], &NA[(3 * 32 + wid * 8) * 64]); \
    gl_lds16(sb[0], &NB[(0 * 32 + wid * 8) * 64]); gl_lds16(sb[1], &NB[(1 * 32 + wid * 8) * 64]); \
    gl_lds16(sb[2], &NB[(2 * 32 + wid * 8) * 64]); gl_lds16(sb[3], &NB[(3 * 32 + wid * 8) * 64]); }
#define D_ADV { _Pragma("unroll") for (int s = 0; s < 4; s++) { sa[s] += 64; sb[s] += 64; } }
#define D_LD(cg, NA, NB) { _Pragma("unroll") for (int i = 0; i < 4; i++) { \
    bfv[i] = __builtin_bit_cast(bf16x8, *(const uint4*)&NB[(wc * 64 + i * 16 + l16) * 64 + (cg) * 8]); \
    afv[i] = __builtin_bit_cast(bf16x8, *(const uint4*)&NA[(wr * 64 + i * 16 + l16) * 64 + (cg) * 8]); } }
#define D_MFMA { _Pragma("unroll") for (int mi = 0; mi < 4; mi++) \
    _Pragma("unroll") for (int ni = 0; ni < 4; ni++) \
        acc[mi][ni] = __builtin_amdgcn_mfma_f32_16x16x32_bf16(bfv[ni], afv[mi], acc[mi][ni], 0, 0, 0); }
#define D_TILE(DAc, DBc, DAn, DBn) { \
    const bool pf = (kt + 1 < NKT); \
    D_LD(cg0, DAc, DBc); \
    if (pf) { D_STG8(DAn, DBn); D_ADV; } \
    __builtin_amdgcn_s_setprio(1); D_MFMA; __builtin_amdgcn_s_setprio(0); \
    D_LD(cg1, DAc, DBc); \
    __builtin_amdgcn_s_setprio(1); D_MFMA; __builtin_amdgcn_s_setprio(0); \
    if (pf) { asm volatile("s_waitcnt vmcnt(0)" ::: "memory"); } \
    phase_bar(); \
    kt++; \
}

    f32x4 acc[4][4] = {};
    const int NKT = K >> 6;

    D_STG8(DA0, DB0); D_ADV;
    asm volatile("s_waitcnt vmcnt(0)" ::: "memory");
    phase_bar();

    int kt = 0;
    bf16x8 bfv[4], afv[4];
    #pragma unroll 1
    for (int kt2 = 0; kt2 < NKT; kt2 += 2) {
        D_TILE(DA0, DB0, DA1, DB1);
        D_TILE(DA1, DB1, DA0, DB0);
    }

    float4 bv4[4];
    #pragma unroll
    for (int ni = 0; ni < 4; ni++)
        bv4[ni] = *(const float4*)&bias[n0 + wc * 64 + ni * 16 + quad * 4];

    #pragma unroll
    for (int mi = 0; mi < 4; mi++) {
        const int m = m0 + wr * 64 + mi * 16 + l16;
        #pragma unroll
        for (int ni = 0; ni < 4; ni++) {
            const int nb2 = n0 + wc * 64 + ni * 16 + quad * 4;
            float v[4] = { acc[mi][ni][0] + bv4[ni].x, acc[mi][ni][1] + bv4[ni].y,
                           acc[mi][ni][2] + bv4[ni].z, acc[mi][ni][3] + bv4[ni].w };
            if (act) {
                #pragma unroll
                for (int r = 0; r < 4; r++) v[r] = gelu_f(v[r]);
            }
            *(uint2*)&out[(size_t)m * N + nb2] = pack4bf(v);
        }
    }
#undef D_STG8
#undef D_ADV
#undef D_LD
#undef D_MFMA
#undef D_TILE
}

// ---------------- MFMA GEMM 256x128 narrow-N (proj, fc2), pipelined, NAMED triple-buffer ----------------
// (round-7 kernel, unchanged) fp32 residual RMW epilogue. Requires NKT % 3 == 0.
__global__ __launch_bounds__(512, 2) void gemmn128_k(const bf16* __restrict__ A, const bf16* __restrict__ BT,
                                                     const float* __restrict__ bias, float* __restrict__ x,
                                                     int N, int K, int ntc)
{
    __shared__ __align__(16) bf16 NA0[256 * 64];
    __shared__ __align__(16) bf16 NA1[256 * 64];
    __shared__ __align__(16) bf16 NA2[256 * 64];
    __shared__ __align__(16) bf16 NB0[128 * 64];
    __shared__ __align__(16) bf16 NB1[128 * 64];
    __shared__ __align__(16) bf16 NB2[128 * 64];

    const int tid  = threadIdx.x;
    const int lane = tid & 63, wid = tid >> 6;
    const int quad = lane >> 4, l16 = lane & 15;
    const int wr = wid >> 1, wc = wid & 1;
    const int cg0 = quad ^ (l16 & 7);
    const int cg1 = cg0 ^ 4;

    int mt, nt;
    supertile_map((int)blockIdx.x, ntc, mt, nt);
    const int m0 = mt * 256, n0 = nt * 128;

    const int srow = wid * 8 + (lane >> 3);
    const int scg  = (lane & 7) ^ (lane >> 3);         // pre-swizzled global col-group
    const bf16* sa[4]; const bf16* sb[2];
    #pragma unroll
    for (int s = 0; s < 4; s++) sa[s] = A  + (size_t)(m0 + s * 64 + srow) * K + scg * 8;
    #pragma unroll
    for (int s = 0; s < 2; s++) sb[s] = BT + (size_t)(n0 + s * 64 + srow) * K + scg * 8;

#define NSTG6(NA, NB) { \
    gl_lds16(sa[0], &NA[(0 * 64 + wid * 8) * 64]); gl_lds16(sa[1], &NA[(1 * 64 + wid * 8) * 64]); \
    gl_lds16(sa[2], &NA[(2 * 64 + wid * 8) * 64]); gl_lds16(sa[3], &NA[(3 * 64 + wid * 8) * 64]); \
    gl_lds16(sb[0], &NB[(0 * 64 + wid * 8) * 64]); gl_lds16(sb[1], &NB[(1 * 64 + wid * 8) * 64]); }
#define NADV { _Pragma("unroll") for (int s = 0; s < 4; s++) sa[s] += 64; sb[0] += 64; sb[1] += 64; }
#define NLD(cg, NA, NB) { _Pragma("unroll") for (int i = 0; i < 4; i++) { \
    bfv[i] = __builtin_bit_cast(bf16x8, *(const uint4*)&NB[(wc * 64 + i * 16 + l16) * 64 + (cg) * 8]); \
    afv[i] = __builtin_bit_cast(bf16x8, *(const uint4*)&NA[(wr * 64 + i * 16 + l16) * 64 + (cg) * 8]); } }
#define NMFMA { _Pragma("unroll") for (int mi = 0; mi < 4; mi++) \
    _Pragma("unroll") for (int ni = 0; ni < 4; ni++) \
        acc[mi][ni] = __builtin_amdgcn_mfma_f32_16x16x32_bf16(bfv[ni], afv[mi], acc[mi][ni], 0, 0, 0); }
#define NITER(NAc, NBc, NAs, NBs) { \
    const bool pf = (kt + 2 < NKT); \
    NLD(cg0, NAc, NBc); \
    if (pf) { NSTG6(NAs, NBs); NADV; } \
    phase_bar(); \
    __builtin_amdgcn_s_setprio(1); NMFMA; __builtin_amdgcn_s_setprio(0); \
    phase_bar(); \
    NLD(cg1, NAc, NBc); \
    phase_bar(); \
    __builtin_amdgcn_s_setprio(1); NMFMA; __builtin_amdgcn_s_setprio(0); \
    if (pf)               { asm volatile("s_waitcnt vmcnt(6)" ::: "memory"); phase_bar(); } \
    else if (kt + 1 < NKT){ asm volatile("s_waitcnt vmcnt(0)" ::: "memory"); phase_bar(); } \
    kt++; \
}

    f32x4 acc[4][4] = {};
    const int NKT = K >> 6;

    NSTG6(NA0, NB0); NADV;
    NSTG6(NA1, NB1); NADV;
    asm volatile("s_waitcnt vmcnt(6)" ::: "memory");
    phase_bar();

    int kt = 0;
    bf16x8 bfv[4], afv[4];
    #pragma unroll 1
    for (int kt3 = 0; kt3 < NKT; kt3 += 3) {
        NITER(NA0, NB0, NA2, NB2);
        NITER(NA1, NB1, NA0, NB0);
        NITER(NA2, NB2, NA1, NB1);
    }

    float4 bv4[4];
    #pragma unroll
    for (int ni = 0; ni < 4; ni++)
        bv4[ni] = *(const float4*)&bias[n0 + wc * 64 + ni * 16 + quad * 4];

    #pragma unroll
    for (int mi = 0; mi < 4; mi++) {
        const int m = m0 + wr * 64 + mi * 16 + l16;
        #pragma unroll
        for (int ni = 0; ni < 4; ni++) {
            const int nb2 = n0 + wc * 64 + ni * 16 + quad * 4;
            float* xp = &x[(size_t)m * N + nb2];
            float4 xo = *(float4*)xp;
            xo.x += acc[mi][ni][0] + bv4[ni].x;
            xo.y += acc[mi][ni][1] + bv4[ni].y;
            xo.z += acc[mi][ni][2] + bv4[ni].z;
            xo.w += acc[mi][ni][3] + bv4[ni].w;
            *(float4*)xp = xo;      // one writer per element: no race
        }
    }
#undef NSTG6
#undef NADV
#undef NLD
#undef NMFMA
#undef NITER
}

// ---------------- MFMA flash attention: 128 queries/block (conflict-free staging, 2 barriers/stage) --
// grid (qt=4, h=12, b=16); block 256 = 4 waves; wave w owns queries w*32..w*32+31 (2 chunks of 16).
// K staged via global_load_lds into LINEAR Kl[128*64] with both-sides XOR swizzle (GEMM pattern);
// V staged via in-register 4-key x 8-dim transpose (uint2 stores, ~2-way banks) into Vt[64][132];
// Ptq is wave-private -> NO barrier between softmax and PV (only 2 barriers per stage).
// LDS 50.7 KB -> 3 blocks/CU.
__global__ __launch_bounds__(256) void attn_k(const bf16* __restrict__ qkv, const int* __restrict__ mask,
                                              bf16* __restrict__ y)
{
    const int qt = blockIdx.x, h = blockIdx.y, b = blockIdx.z;
    const int qbase = qt * 128, tokb = b * 512;
    __shared__ __align__(16) bf16 Kl[128 * 64];
    __shared__ __align__(16) unsigned short Vt[64][132];
    __shared__ __align__(16) unsigned short Ptq[4][16][132];
    __shared__ float mkf[128];

    const int tid = threadIdx.x, wave = tid >> 6, lane = tid & 63;
    const int quad = lane >> 4, l16 = lane & 15;
    const int cgq0 = quad ^ (l16 & 7);          // physical col-group for K dims 0..31
    const int cgq1 = cgq0 ^ 4;                  // dims 32..63

    // K staging source (pre-swizzled, GEMM pattern): sweep s covers keys s*32..s*32+31
    const int srow = wave * 8 + (lane >> 3);    // [0,32)
    const int scg  = (lane & 7) ^ (lane >> 3);

    // V transpose mapping: thread handles keys kb..kb+3, dims d0..d0+7
    const int kb = (tid & 31) * 4;
    const int d0v = (tid >> 5) * 8;

    // Q fragments for both chunks, direct from global (L2-resident)
    bf16x8 bq[2][2];
    #pragma unroll
    for (int qc = 0; qc < 2; qc++) {
        const bf16* qp = &qkv[(size_t)(tokb + qbase + wave * 32 + qc * 16 + l16) * 2304 + h * 64];
        bq[qc][0] = __builtin_bit_cast(bf16x8, *(const uint4*)(qp + quad * 8));
        bq[qc][1] = __builtin_bit_cast(bf16x8, *(const uint4*)(qp + 32 + quad * 8));
    }

    float m_i[2] = { -INFINITY, -INFINITY }, l_i[2] = { 0.f, 0.f };
    f32x4 Oacc[2][4] = {};

    const int nst = qt + 1;
    for (int s = 0; s < nst; s++) {
        const int j0 = s * 128;
        __syncthreads();    // WAR: Kl/Vt/mkf from previous stage
        {
            // K: global_load_lds, linear dest, swizzled source (4 sweeps x 32 keys)
            #pragma unroll
            for (int sw = 0; sw < 4; sw++)
                gl_lds16(&qkv[(size_t)(tokb + j0 + sw * 32 + srow) * 2304 + 768 + h * 64 + scg * 8],
                         &Kl[(sw * 32 + wave * 8) * 64]);
            // V: in-register 4x8 transpose, vectorized stores
            union { uint4 u; unsigned short e[8]; } vv[4];
            #pragma unroll
            for (int i = 0; i < 4; i++)
                vv[i].u = *(const uint4*)&qkv[(size_t)(tokb + j0 + kb + i) * 2304 + 1536 + h * 64 + d0v];
            #pragma unroll
            for (int j = 0; j < 8; j++) {
                union { unsigned short e[4]; uint2 u; } pk;
                #pragma unroll
                for (int i = 0; i < 4; i++) pk.e[i] = vv[i].e[j];
                *(uint2*)&Vt[d0v + j][kb] = pk.u;
            }
            if (tid < 128) mkf[tid] = mask[b * 512 + j0 + tid] ? 0.f : -INFINITY;
        }
        __syncthreads();    // publish Kl (drains vmcnt for gl_lds) + Vt + mkf

        #pragma unroll
        for (int qc = 0; qc < 2; qc++) {
            const int qi = qbase + wave * 32 + qc * 16 + l16;

            // S^T = K · Q^T (K from swizzled LDS)
            f32x4 sc[8] = {};
            #pragma unroll
            for (int kcc = 0; kcc < 8; kcc++) {
                bf16x8 af0 = __builtin_bit_cast(bf16x8, *(const uint4*)&Kl[(kcc * 16 + l16) * 64 + cgq0 * 8]);
                bf16x8 af1 = __builtin_bit_cast(bf16x8, *(const uint4*)&Kl[(kcc * 16 + l16) * 64 + cgq1 * 8]);
                sc[kcc] = __builtin_amdgcn_mfma_f32_16x16x32_bf16(af0, bq[qc][0], sc[kcc], 0, 0, 0);
                sc[kcc] = __builtin_amdgcn_mfma_f32_16x16x32_bf16(af1, bq[qc][1], sc[kcc], 0, 0, 0);
            }

            float pv[8][4];
            float mx = -INFINITY;
            #pragma unroll
            for (int kcc = 0; kcc < 8; kcc++) {
                float4 mk4 = *(const float4*)&mkf[kcc * 16 + quad * 4];
                float mkr[4] = { mk4.x, mk4.y, mk4.z, mk4.w };
                #pragma unroll
                for (int r = 0; r < 4; r++) {
                    int krel = kcc * 16 + quad * 4 + r;
                    float sval = (j0 + krel <= qi) ? (sc[kcc][r] * 0.125f + mkr[r]) : -INFINITY;
                    pv[kcc][r] = sval;
                    mx = fmaxf(mx, sval);
                }
            }
            mx = fmaxf(mx, __shfl_xor(mx, 16, 64));
            mx = fmaxf(mx, __shfl_xor(mx, 32, 64));
            float mn = fmaxf(m_i[qc], mx);
            float alpha = (mn == -INFINITY) ? 1.f : __expf(m_i[qc] - mn);
            float lsum = 0.f;
            #pragma unroll
            for (int kcc = 0; kcc < 8; kcc++)
                #pragma unroll
                for (int r = 0; r < 4; r++) {
                    float pp = (pv[kcc][r] == -INFINITY) ? 0.f : __expf(pv[kcc][r] - mn);
                    pv[kcc][r] = pp; lsum += pp;
                }
            lsum += __shfl_xor(lsum, 16, 64);
            lsum += __shfl_xor(lsum, 32, 64);
            m_i[qc] = mn; l_i[qc] = alpha * l_i[qc] + lsum;

            // P -> wave-private LDS slice (no cross-wave barrier needed)
            #pragma unroll
            for (int kcc = 0; kcc < 8; kcc++)
                *(uint2*)&Ptq[wave][l16][kcc * 16 + quad * 4] = pack4bf(pv[kcc]);
            #pragma unroll
            for (int mc = 0; mc < 4; mc++)
                #pragma unroll
                for (int r = 0; r < 4; r++) Oacc[qc][mc][r] *= alpha;

            #pragma unroll
            for (int kcc = 0; kcc < 4; kcc++) {
                bf16x8 pb = __builtin_bit_cast(bf16x8, *(const uint4*)&Ptq[wave][l16][kcc * 32 + quad * 8]);
                #pragma unroll
                for (int mc = 0; mc < 4; mc++) {
                    bf16x8 vf = __builtin_bit_cast(bf16x8, *(const uint4*)&Vt[mc * 16 + l16][kcc * 32 + quad * 8]);
                    Oacc[qc][mc] = __builtin_amdgcn_mfma_f32_16x16x32_bf16(vf, pb, Oacc[qc][mc], 0, 0, 0);
                }
            }
        }
    }

    #pragma unroll
    for (int qc = 0; qc < 2; qc++) {
        float inv = (l_i[qc] > 0.f) ? 1.f / l_i[qc] : 0.f;   // fully-masked row -> 0
        const int tok = tokb + qbase + wave * 32 + qc * 16 + l16;
        #pragma unroll
        for (int mc = 0; mc < 4; mc++) {
            float v[4] = { Oacc[qc][mc][0] * inv, Oacc[qc][mc][1] * inv,
                           Oacc[qc][mc][2] * inv, Oacc[qc][mc][3] * inv };
            *(uint2*)&y[(size_t)tok * 768 + h * 64 + mc * 16 + quad * 4] = pack4bf(v);
        }
    }
}

// ---------------- final LN + last-token select + head (fp32) ----------------
__global__ __launch_bounds__(256) void head_k(const float* __restrict__ x, const int* __restrict__ lastidx,
                                              const float* __restrict__ ls, const float* __restrict__ lb,
                                              const float* __restrict__ hw, const float* __restrict__ hb,
                                              float* __restrict__ out)
{
    int b = blockIdx.x, tid = threadIdx.x;
    const float* xr = x + ((size_t)(b * 512 + lastidx[b])) * 768;
    float v0 = xr[tid], v1 = xr[tid + 256], v2 = xr[tid + 512];
    __shared__ float rs[256], rq[256];
    rs[tid] = v0 + v1 + v2; rq[tid] = v0 * v0 + v1 * v1 + v2 * v2;
    __syncthreads();
    for (int st = 128; st > 0; st >>= 1) {
        if (tid < st) { rs[tid] += rs[tid + st]; rq[tid] += rq[tid + st]; }
        __syncthreads();
    }
    float mean = rs[0] * (1.f / 768.f);
    float var  = rq[0] * (1.f / 768.f) - mean * mean;
    float rstd = rsqrtf(var + 1e-5f);
    float part[9];
    #pragma unroll
    for (int a = 0; a < 9; a++) part[a] = 0.f;
    float vv[3] = { v0, v1, v2 };
    #pragma unroll
    for (int e = 0; e < 3; e++) {
        int d = tid + e * 256;
        float xnv = (vv[e] - mean) * rstd * ls[d] + lb[d];
        #pragma unroll
        for (int a = 0; a < 9; a++) part[a] += xnv * hw[d * 9 + a];
    }
    __shared__ float r9[9][256];
    #pragma unroll
    for (int a = 0; a < 9; a++) r9[a][tid] = part[a];
    __syncthreads();
    for (int st = 128; st > 0; st >>= 1) {
        if (tid < st) {
            for (int a = 0; a < 9; a++) r9[a][tid] += r9[a][tid + st];
        }
        __syncthreads();
    }
    if (tid < 9) out[b * 9 + tid] = r9[tid][0] + hb[tid];
}

extern "C" void kernel_launch(void* const* d_in, const int* in_sizes, int n_in,
                              void* d_out, int out_size, void* d_ws, size_t ws_size,
                              hipStream_t stream) {
    const int*   cards   = (const int*)  d_in[0];
    const int*   players = (const int*)  d_in[1];
    const int*   deck    = (const int*)  d_in[2];
    const int*   oppd    = (const int*)  d_in[3];
    const float* tok     = (const float*)d_in[4];
    const float* pemb    = (const float*)d_in[5];
    const float* pos     = (const float*)d_in[6];
    const float* ln1s  = (const float*)d_in[9];
    const float* ln1b  = (const float*)d_in[10];
    const float* qkvw  = (const float*)d_in[11];
    const float* qkvb  = (const float*)d_in[12];
    const float* projw = (const float*)d_in[13];
    const float* projb = (const float*)d_in[14];
    const float* ln2s  = (const float*)d_in[15];
    const float* ln2b  = (const float*)d_in[16];
    const float* fc1w  = (const float*)d_in[17];
    const float* fc1b  = (const float*)d_in[18];
    const float* fc2w  = (const float*)d_in[19];
    const float* fc2b  = (const float*)d_in[20];
    const float* lnfs  = (const float*)d_in[21];
    const float* lnfb  = (const float*)d_in[22];
    const float* hw    = (const float*)d_in[23];
    const float* hb    = (const float*)d_in[24];
    float* out = (float*)d_out;

    char* p = (char*)d_ws;
    auto alloc = [&](size_t bytes) { char* q = p; p += (bytes + 255) & ~((size_t)255); return q; };
    float* x     = (float*)alloc(8192ull * 768 * 4);
    bf16*  xn    = (bf16*) alloc(8192ull * 768 * 2);
    bf16*  big   = (bf16*) alloc(8192ull * 3072 * 2);
    bf16*  wt    = (bf16*) alloc(7077888ull * 2);      // all 4 transposed mats of one layer
    float* deckm = (float*)alloc(2ull * 16 * 768 * 4);
    int*   maskb = (int*)  alloc(8192ull * 4);
    int*   lasti = (int*)  alloc(64);

    bf16* wq = wt;                        // [2304][768]
    bf16* wp = wq + 2304ull * 768;        // [768][768]
    bf16* w1 = wp + 768ull * 768;         // [3072][768]
    bf16* w2 = w1 + 3072ull * 768;        // [768][3072]

    deckmean_k<<<dim3(16, 2), 256, 0, stream>>>(deck, oppd, tok, deckm);
    mask_k<<<16, 512, 0, stream>>>(cards, maskb, lasti);
    embed_k<<<8192, 256, 0, stream>>>(cards, players, tok, pemb, pos, deckm, x);

    for (int i = 0; i < 6; i++) {
        transpose4_k<<<1728, 256, 0, stream>>>(
            qkvw + (size_t)i * 768 * 2304, projw + (size_t)i * 768 * 768,
            fc1w + (size_t)i * 768 * 3072, fc2w + (size_t)i * 3072 * 768,
            wq, wp, w1, w2);

        // attention block
        ln_k<<<8192, 192, 0, stream>>>(x, ln1s + i * 768, ln1b + i * 768, xn);
        gemm2b_k<<<1152, 256, 0, stream>>>(xn, wq, qkvb + i * 2304, big, 2304, 768, 0, 6);
        attn_k<<<dim3(4, 12, 16), 256, 0, stream>>>(big, maskb, xn);
        gemmn128_k<<<192, 512, 0, stream>>>(xn, wp, projb + i * 768, x, 768, 768, 6);
        // MLP block
        ln_k<<<8192, 192, 0, stream>>>(x, ln2s + i * 768, ln2b + i * 768, xn);
        gemm2b_k<<<1536, 256, 0, stream>>>(xn, w1, fc1b + i * 3072, big, 3072, 768, 1, 8);
        gemmn128_k<<<192, 512, 0, stream>>>(big, w2, fc2b + i * 768, x, 768, 3072, 6);
    }

    head_k<<<16, 256, 0, stream>>>(x, lasti, lnfs, lnfb, hw, hb, out);
}